// Round 20
// baseline (136.078 us; speedup 1.0000x reference)
//
#include <hip/hip_runtime.h>

#define NB   4
#define H_IN 14
#define W_IN 14
#define FIN  32
#define DI   8
#define F    32
#define C    288   // 3*3*32
#define DO   16
#define HO   12
#define WO   12
#define NPOS (NB*HO*WO)   // 576
#define EPS  1e-7f

#define CH   16            // c-chunks (kern2)
#define CC   (C/CH)        // 18
#define GP   8             // positions per block in kern2
#define GRID (CH*(NPOS/GP))// 1152

#define KTOT (C*DI)        // 2304 = K of the cent1 GEMM
#define KPAD 2312          // LDS row pad: 1156 words % 32 = 4 -> conflict-free

#define W2H_BYTES  ((size_t)F*C*DO*DI*2)       // 2,359,296  (transposed, kern2)
#define WH_BYTES   ((size_t)F*C*DO*DI*2)       // 2,359,296  (orig layout, MFMA B)
#define PH_BYTES   ((size_t)NPOS*KTOT*2)       // 2,654,208  (patch matrix fp16)
#define PART_BYTES ((size_t)CH*NPOS*F*DO*2)    // 9,437,184  (part2 fp16)
#define OUT1_BYTES ((size_t)NPOS*F*DO*4)       // 1,179,648

#define CVT_W2H 576
#define CVT_WH  576        // 147456 uint4
#define CVT_PH  648        // 165888 uint4
#define CVT_GRID (CVT_W2H + CVT_WH + CVT_PH)

typedef _Float16 h2 __attribute__((ext_vector_type(2)));
typedef _Float16 h8v __attribute__((ext_vector_type(8)));
typedef float    f4v __attribute__((ext_vector_type(4)));

__device__ __forceinline__ unsigned int pack2(float a, float b) {
    h2 v; v.x = (_Float16)a; v.y = (_Float16)b;
    return __builtin_bit_cast(unsigned int, v);
}

// 8-term fp16 dot with fp32 accumulate
__device__ __forceinline__ float dot8h(const uint4 w, const uint4 v, float acc) {
#if __has_builtin(__builtin_amdgcn_fdot2)
    acc = __builtin_amdgcn_fdot2(__builtin_bit_cast(h2, w.x), __builtin_bit_cast(h2, v.x), acc, false);
    acc = __builtin_amdgcn_fdot2(__builtin_bit_cast(h2, w.y), __builtin_bit_cast(h2, v.y), acc, false);
    acc = __builtin_amdgcn_fdot2(__builtin_bit_cast(h2, w.z), __builtin_bit_cast(h2, v.z), acc, false);
    acc = __builtin_amdgcn_fdot2(__builtin_bit_cast(h2, w.w), __builtin_bit_cast(h2, v.w), acc, false);
#else
    const h2 w0 = __builtin_bit_cast(h2, w.x), v0 = __builtin_bit_cast(h2, v.x);
    const h2 w1 = __builtin_bit_cast(h2, w.y), v1 = __builtin_bit_cast(h2, v.y);
    const h2 w2 = __builtin_bit_cast(h2, w.z), v2 = __builtin_bit_cast(h2, v.z);
    const h2 w3 = __builtin_bit_cast(h2, w.w), v3 = __builtin_bit_cast(h2, v.w);
    acc += (float)w0.x*(float)v0.x + (float)w0.y*(float)v0.y
         + (float)w1.x*(float)v1.x + (float)w1.y*(float)v1.y
         + (float)w2.x*(float)v2.x + (float)w2.y*(float)v2.y
         + (float)w3.x*(float)v3.x + (float)w3.y*(float)v3.y;
#endif
    return acc;
}

__device__ __forceinline__ int xbase_of(int pos) {
    const int b = pos/(HO*WO), rem = pos%(HO*WO), ho = rem/WO, wo = rem%WO;
    return ((b*H_IN + ho)*W_IN + wo)*FIN*DI;
}

__device__ __forceinline__ int coff_of(int c) {
    const int slab = c >> 5, fin = c & 31;
    const int kh = slab/3, kw = slab%3;
    return (kh*W_IN + kw)*FIN*DI + fin*DI;
}

// ---- conversion (coalesced READS; scattered writes absorbed by L2) ------------
__global__ __launch_bounds__(256) void kernConv(const float* __restrict__ Wt,
                                                const float* __restrict__ x,
                                                unsigned short* __restrict__ W2h,
                                                unsigned short* __restrict__ Wh,
                                                unsigned short* __restrict__ Ph) {
    const int b = blockIdx.x;
    if (b < CVT_W2H) {                 // W2h[c][o][f][i] <- W[f][c][o][i]
        const int idx = b*256 + threadIdx.x;
        const float* src = Wt + (size_t)idx*8;     // coalesced read
        const float4 a = *(const float4*)src;
        const float4 bb = *(const float4*)(src + 4);
        uint4 r;
        r.x = pack2(a.x, a.y);   r.y = pack2(a.z, a.w);
        r.z = pack2(bb.x, bb.y); r.w = pack2(bb.z, bb.w);
        const int o = idx & 15;
        const int c = (idx >> 4) % C;
        const int f = idx / (C*DO);
        ((uint4*)W2h)[(size_t)(c*DO + o)*F + f] = r;
    } else if (b < CVT_W2H + CVT_WH) { // Wh = fp16(Wt), same layout
        const int idx = (b - CVT_W2H)*256 + threadIdx.x;
        const float* src = Wt + (size_t)idx*8;
        const float4 a = *(const float4*)src;
        const float4 bb = *(const float4*)(src + 4);
        uint4 r;
        r.x = pack2(a.x, a.y);   r.y = pack2(a.z, a.w);
        r.z = pack2(bb.x, bb.y); r.w = pack2(bb.z, bb.w);
        ((uint4*)Wh)[idx] = r;
    } else {                           // Ph[pos][c*8+i]
        const int pc = (b - CVT_W2H - CVT_WH)*256 + threadIdx.x;
        const int pos = pc / C, c = pc % C;
        const float* src = x + xbase_of(pos) + coff_of(c);
        const float4 a = *(const float4*)src;
        const float4 bb = *(const float4*)(src + 4);
        uint4 r;
        r.x = pack2(a.x, a.y);   r.y = pack2(a.z, a.w);
        r.z = pack2(bb.x, bb.y); r.w = pack2(bb.z, bb.w);
        ((uint4*)Ph)[pc] = r;
    }
}

// ---- kernM1: cent1 GEMM via MFMA + fused squash -> out1 (R19-proven). ---------
__global__ __launch_bounds__(256) void kernM1(const unsigned short* __restrict__ Ph,
                                              const unsigned short* __restrict__ Wh,
                                              float* __restrict__ out1)
{
    __shared__ unsigned short As[16][KPAD];       // 73,984 B

    const int tid  = threadIdx.x;
    const int lane = tid & 63;
    const int wv   = tid >> 6;
    const int pt   = blockIdx.x >> 3;             // 0..35
    const int fg   = blockIdx.x & 7;              // 0..7
    const int f    = wv*8 + fg;
    const int pos0 = pt*16;
    const int n    = lane & 15, q = lane >> 4;

    #pragma unroll
    for (int r = 0; r < 18; ++r) {
        const int linear = r*256 + tid;
        const int row = linear / 288, col8 = linear % 288;
        const uint4 v = *(const uint4*)(Ph + (size_t)(pos0 + row)*KTOT + col8*8);
        *(uint4*)&As[row][col8*8] = v;
    }
    __syncthreads();

    const unsigned short* pa = &As[n][q*8];
    const unsigned short* pb = Wh + ((size_t)(f*C + q)*DO + n)*DI;

    f4v acc0 = {0.f,0.f,0.f,0.f}, acc1 = {0.f,0.f,0.f,0.f};
    #pragma unroll 4
    for (int s = 0; s < KTOT/32; s += 2) {
        const h8v a0 = *(const h8v*)(pa + s*32);
        const h8v b0 = *(const h8v*)(pb + (size_t)s*4*DO*DI);
        const h8v a1 = *(const h8v*)(pa + (s+1)*32);
        const h8v b1 = *(const h8v*)(pb + (size_t)(s+1)*4*DO*DI);
        acc0 = __builtin_amdgcn_mfma_f32_16x16x32_f16(a0, b0, acc0, 0, 0, 0);
        acc1 = __builtin_amdgcn_mfma_f32_16x16x32_f16(a1, b1, acc1, 0, 0, 0);
    }

    #pragma unroll
    for (int r = 0; r < 4; ++r) {
        const float v = (acc0[r] + acc1[r]) * (1.f/32.f);
        float sq = v*v;
        sq += __shfl_xor(sq, 1);
        sq += __shfl_xor(sq, 2);
        sq += __shfl_xor(sq, 4);
        sq += __shfl_xor(sq, 8);
        const float sc = (sq/(1.f + sq)) * rsqrtf(sq + EPS);
        out1[(size_t)(pos0 + q*4 + r)*512 + f*DO + n] = v * sc;
    }
}

// ---- kern2: c-PAIR iterations (2 softmaxes per barrier-pair); fp16 part2. -----
// writes part2h[ch][pos][f][o] fp16
__global__ __launch_bounds__(256) void kern2n(const unsigned short* __restrict__ Ph,
                                              const unsigned short* __restrict__ W2h,
                                              const float* __restrict__ out1,
                                              unsigned short* __restrict__ part2h)
{
    __shared__ float red[2][4][GP][32];  // 8 KB (one buf per sub-c)
    __shared__ float ccs[2][GP][32];     // 2 KB

    const int tid = threadIdx.x;
    const int f  = tid & 31;
    const int og = tid >> 5;            // 0..7
    const int o0 = 2*og, o1 = o0 + 1;
    const int wv = tid >> 6;            // wave 0..3
    const int half = (tid >> 5) & 1;    // og parity within wave
    const int ch = blockIdx.x & (CH-1);
    const int pg = blockIdx.x >> 4;     // 0..71

    int poff[GP];                       // block-uniform -> SGPRs
    #pragma unroll
    for (int p = 0; p < GP; ++p) poff[p] = (pg*GP + p)*KTOT;

    float u0[GP], u1[GP];
    #pragma unroll
    for (int p = 0; p < GP; ++p) {
        const float* up = out1 + (size_t)(pg*GP + p)*512 + f*DO;
        u0[p] = up[o0];
        u1[p] = up[o1];
    }

    const uint4* W2h4 = (const uint4*)W2h;
    const int c0 = ch*CC;

    float acc0[GP], acc1[GP];
    #pragma unroll
    for (int p = 0; p < GP; ++p) { acc0[p] = 0.f; acc1[p] = 0.f; }

    #pragma unroll 1
    for (int cp = 0; cp < CC/2; ++cp) {           // 9 pair-iterations
        const int ca = c0 + cp*2, cb = ca + 1;
        const uint4 wa0 = W2h4[(size_t)(ca*DO + o0)*F + f];
        const uint4 wa1 = W2h4[(size_t)(ca*DO + o1)*F + f];
        const uint4 wb0 = W2h4[(size_t)(cb*DO + o0)*F + f];
        const uint4 wb1 = W2h4[(size_t)(cb*DO + o1)*F + f];

        float pa0[GP], pa1[GP], pb0[GP], pb1[GP];
        #pragma unroll
        for (int p = 0; p < GP; ++p) {
            const uint4 xa = *(const uint4*)(Ph + poff[p] + ca*DI);  // uniform
            const uint4 xb = *(const uint4*)(Ph + poff[p] + cb*DI);  // uniform
            pa0[p] = dot8h(wa0, xa, 0.f);
            pa1[p] = dot8h(wa1, xa, 0.f);
            pb0[p] = dot8h(wb0, xb, 0.f);
            pb1[p] = dot8h(wb1, xb, 0.f);
        }

        // agr partials for both sub-c's
        #pragma unroll
        for (int p = 0; p < GP; ++p) {
            float apa = pa0[p]*u0[p] + pa1[p]*u1[p];
            float apb = pb0[p]*u0[p] + pb1[p]*u1[p];
            apa += __shfl_xor(apa, 32);
            apb += __shfl_xor(apb, 32);
            if (half == 0) {
                red[0][wv][p][f] = apa;
                red[1][wv][p][f] = apb;
            }
        }
        __syncthreads();

        // remap: 2 softmaxes (one per sub-c)
        {
            const int p2 = tid >> 5, f2 = tid & 31;
            #pragma unroll
            for (int sub = 0; sub < 2; ++sub) {
                const float agr = red[sub][0][p2][f2] + red[sub][1][p2][f2]
                                + red[sub][2][p2][f2] + red[sub][3][p2][f2];
                float m = agr;
                m = fmaxf(m, __shfl_xor(m, 1));
                m = fmaxf(m, __shfl_xor(m, 2));
                m = fmaxf(m, __shfl_xor(m, 4));
                m = fmaxf(m, __shfl_xor(m, 8));
                m = fmaxf(m, __shfl_xor(m, 16));
                const float e = __expf(agr - m);
                float s = e;
                s += __shfl_xor(s, 1);
                s += __shfl_xor(s, 2);
                s += __shfl_xor(s, 4);
                s += __shfl_xor(s, 8);
                s += __shfl_xor(s, 16);
                ccs[sub][p2][f2] = e / s;
            }
        }
        __syncthreads();

        // accumulate cent2 for both sub-c's
        #pragma unroll
        for (int p = 0; p < GP; ++p) {
            const float cva = ccs[0][p][f];
            const float cvb = ccs[1][p][f];
            acc0[p] += cva*pa0[p] + cvb*pb0[p];
            acc1[p] += cva*pa1[p] + cvb*pb1[p];
        }
    }

    // store fp16 partials: part2h[ch][pos][f][o], one packed dword per (p, o-pair)
    #pragma unroll
    for (int p = 0; p < GP; ++p) {
        const size_t base = ((size_t)(ch*NPOS + pg*GP + p)*F + f)*DO;
        ((unsigned int*)(part2h + base))[og] = pack2(acc0[p], acc1[p]);
    }
}

// ---- kern3: reduce fp16 cent2 partials ([ch][pos][f][o]), squash, store. ------
__global__ __launch_bounds__(256) void kern3(const unsigned short* __restrict__ part2h,
                                             float* __restrict__ out)
{
    const int tid = threadIdx.x;
    const int f = tid & 31, p = tid >> 5;
    const int pos = blockIdx.x*8 + p;

    float cent[DO];
    #pragma unroll
    for (int o = 0; o < DO; ++o) cent[o] = 0.f;
    #pragma unroll 1
    for (int k = 0; k < CH; ++k) {
        const uint4* s = (const uint4*)(part2h + ((size_t)(k*NPOS + pos)*F + f)*DO);
        const uint4 v0 = s[0], v1 = s[1];
        const unsigned int w[8] = {v0.x, v0.y, v0.z, v0.w, v1.x, v1.y, v1.z, v1.w};
        #pragma unroll
        for (int q = 0; q < 8; ++q) {
            const h2 hv = __builtin_bit_cast(h2, w[q]);
            cent[2*q]   += (float)hv.x;
            cent[2*q+1] += (float)hv.y;
        }
    }
    float sn = 0.f;
    #pragma unroll
    for (int o = 0; o < DO; ++o) sn += cent[o]*cent[o];
    const float sc = (sn/(1.f + sn)) * rsqrtf(sn + EPS);
    float4* dst = (float4*)(out + ((size_t)pos*F + f)*DO);
    dst[0] = make_float4(cent[0]*sc,  cent[1]*sc,  cent[2]*sc,  cent[3]*sc);
    dst[1] = make_float4(cent[4]*sc,  cent[5]*sc,  cent[6]*sc,  cent[7]*sc);
    dst[2] = make_float4(cent[8]*sc,  cent[9]*sc,  cent[10]*sc, cent[11]*sc);
    dst[3] = make_float4(cent[12]*sc, cent[13]*sc, cent[14]*sc, cent[15]*sc);
}

// -------- fp32 single-kernel fallback (only if ws too small) -------------------
__device__ __forceinline__ float dot8(const float4* __restrict__ w,
                                      const float4 p0, const float4 p1) {
    float4 a = w[0], b = w[1];
    return a.x*p0.x + a.y*p0.y + a.z*p0.z + a.w*p0.w
         + b.x*p1.x + b.y*p1.y + b.z*p1.z + b.w*p1.w;
}

__global__ __launch_bounds__(256) void capsule_kernel_f32(
    const float* __restrict__ x, const float* __restrict__ Wt,
    float* __restrict__ out)
{
    __shared__ float patch[C*DI];
    __shared__ float cent[F*DO];
    __shared__ float out1[F*DO];
    __shared__ float agr[F*C];
    __shared__ float scale_s[F];

    const int tid = threadIdx.x;
    const int pos = blockIdx.x;
    const int b   = pos / (HO*WO);
    const int rem = pos % (HO*WO);
    const int ho  = rem / WO;
    const int wo  = rem % WO;

    #pragma unroll
    for (int slab = 0; slab < 9; ++slab) {
        const int kh = slab / 3, kw = slab % 3;
        const float* src = x + (((b*H_IN + ho + kh)*W_IN + (wo + kw))*FIN)*DI;
        patch[slab*256 + tid] = src[tid];
    }
    __syncthreads();

    const float4* pv = (const float4*)patch;

    {
        const int fo0 = tid, fo1 = tid + 256;
        const int f0 = fo0 >> 4, o0 = fo0 & 15;
        const int f1 = fo1 >> 4, o1 = fo1 & 15;
        float acc0 = 0.f, acc1 = 0.f;
        for (int c = 0; c < C; ++c) {
            const float4 p0 = pv[c*2], p1 = pv[c*2+1];
            acc0 += dot8((const float4*)(Wt + ((f0*C + c)*DO + o0)*DI), p0, p1);
            acc1 += dot8((const float4*)(Wt + ((f1*C + c)*DO + o1)*DI), p0, p1);
        }
        cent[fo0] = acc0 * (1.f/32.f);
        cent[fo1] = acc1 * (1.f/32.f);
    }
    __syncthreads();

    if (tid < F) {
        float sn = 0.f;
        #pragma unroll
        for (int o = 0; o < DO; ++o) { float v = cent[tid*DO + o]; sn += v*v; }
        const float sc = (sn/(1.f + sn)) * rsqrtf(sn + EPS);
        #pragma unroll
        for (int o = 0; o < DO; ++o) out1[tid*DO + o] = cent[tid*DO + o] * sc;
    }
    __syncthreads();

    #pragma unroll 1
    for (int r = 0; r < (F*C)/256; ++r) {
        const int pp = tid + 256*r;
        const int f = pp / C, c = pp % C;
        const float4* wrow = (const float4*)(Wt + (f*C + c)*DO*DI);
        const float4 p0 = pv[c*2], p1 = pv[c*2+1];
        float a = 0.f;
        #pragma unroll
        for (int o = 0; o < DO; ++o) a += dot8(wrow + o*2, p0, p1) * out1[f*DO + o];
        agr[pp] = a;
    }
    __syncthreads();

    for (int c = tid; c < C; c += 256) {
        float m = -1e30f;
        #pragma unroll
        for (int f = 0; f < F; ++f) m = fmaxf(m, agr[f*C + c]);
        float s = 0.f;
        #pragma unroll
        for (int f = 0; f < F; ++f) {
            const float e = __expf(agr[f*C + c] - m);
            agr[f*C + c] = e; s += e;
        }
        const float inv = 1.f / s;
        #pragma unroll
        for (int f = 0; f < F; ++f) agr[f*C + c] *= inv;
    }
    __syncthreads();

    {
        const int fo0 = tid, fo1 = tid + 256;
        const int f0 = fo0 >> 4, o0 = fo0 & 15;
        const int f1 = fo1 >> 4, o1 = fo1 & 15;
        float acc0 = 0.f, acc1 = 0.f;
        for (int c = 0; c < C; ++c) {
            const float4 p0 = pv[c*2], p1 = pv[c*2+1];
            acc0 += agr[f0*C + c] * dot8((const float4*)(Wt + ((f0*C + c)*DO + o0)*DI), p0, p1);
            acc1 += agr[f1*C + c] * dot8((const float4*)(Wt + ((f1*C + c)*DO + o1)*DI), p0, p1);
        }
        cent[fo0] = acc0;
        cent[fo1] = acc1;
    }
    __syncthreads();

    if (tid < F) {
        float sn = 0.f;
        #pragma unroll
        for (int o = 0; o < DO; ++o) { float v = cent[tid*DO + o]; sn += v*v; }
        scale_s[tid] = (sn/(1.f + sn)) * rsqrtf(sn + EPS);
    }
    __syncthreads();

    out[pos*(F*DO) + tid]       = cent[tid]       * scale_s[tid >> 4];
    out[pos*(F*DO) + tid + 256] = cent[tid + 256] * scale_s[(tid >> 4) + 16];
}

extern "C" void kernel_launch(void* const* d_in, const int* in_sizes, int n_in,
                              void* d_out, int out_size, void* d_ws, size_t ws_size,
                              hipStream_t stream) {
    const float* x  = (const float*)d_in[0];
    const float* Wt = (const float*)d_in[1];
    float* out = (float*)d_out;

    if (ws_size >= W2H_BYTES + WH_BYTES + PH_BYTES + PART_BYTES + OUT1_BYTES) {
        char* p = (char*)d_ws;
        unsigned short* W2h = (unsigned short*)p;            p += W2H_BYTES;
        unsigned short* Wh  = (unsigned short*)p;            p += WH_BYTES;
        unsigned short* Ph  = (unsigned short*)p;            p += PH_BYTES;
        unsigned short* part2h = (unsigned short*)p;         p += PART_BYTES;
        float* out1 = (float*)p;

        kernConv<<<CVT_GRID, 256, 0, stream>>>(Wt, x, W2h, Wh, Ph);  // 1800 blocks
        kernM1<<<36*8, 256, 0, stream>>>(Ph, Wh, out1);              // 288 blocks
        kern2n<<<GRID, 256, 0, stream>>>(Ph, W2h, out1, part2h);     // 1152 blocks
        kern3<<<NPOS/8, 256, 0, stream>>>(part2h, out);              // 72 blocks
    } else {
        capsule_kernel_f32<<<NPOS, 256, 0, stream>>>(x, Wt, out);
    }
}

// Round 21
// 133.441 us; speedup vs baseline: 1.0198x; 1.0198x over previous
//
#include <hip/hip_runtime.h>

#define NB   4
#define H_IN 14
#define W_IN 14
#define FIN  32
#define DI   8
#define F    32
#define C    288   // 3*3*32
#define DO   16
#define HO   12
#define WO   12
#define NPOS (NB*HO*WO)   // 576
#define EPS  1e-7f

#define CH   16            // c-chunks (kern2)
#define CC   (C/CH)        // 18
#define GP   8             // positions per block in kern2 (R15-proven)
#define GRID (CH*(NPOS/GP))// 1152

#define KTOT (C*DI)        // 2304 = K of the cent1 GEMM
#define KPAD 2312          // LDS row pad: 1156 words % 32 = 4 -> conflict-free

#define W2H_BYTES  ((size_t)F*C*DO*DI*2)       // 2,359,296  (transposed, kern2)
#define WH_BYTES   ((size_t)F*C*DO*DI*2)       // 2,359,296  (orig layout, MFMA B)
#define PH_BYTES   ((size_t)NPOS*KTOT*2)       // 2,654,208  (patch matrix fp16)
#define PART_BYTES ((size_t)CH*NPOS*F*DO*4)    // 18,874,368 (part2 fp32)
#define OUT1_BYTES ((size_t)NPOS*F*DO*4)       // 1,179,648

#define CVT_W2H 576
#define CVT_WH  576        // 147456 uint4
#define CVT_PH  648        // 165888 uint4
#define CVT_GRID (CVT_W2H + CVT_WH + CVT_PH)

typedef _Float16 h2 __attribute__((ext_vector_type(2)));
typedef _Float16 h8v __attribute__((ext_vector_type(8)));
typedef float    f4v __attribute__((ext_vector_type(4)));

__device__ __forceinline__ unsigned int pack2(float a, float b) {
    h2 v; v.x = (_Float16)a; v.y = (_Float16)b;
    return __builtin_bit_cast(unsigned int, v);
}

// 8-term fp16 dot with fp32 accumulate
__device__ __forceinline__ float dot8h(const uint4 w, const uint4 v, float acc) {
#if __has_builtin(__builtin_amdgcn_fdot2)
    acc = __builtin_amdgcn_fdot2(__builtin_bit_cast(h2, w.x), __builtin_bit_cast(h2, v.x), acc, false);
    acc = __builtin_amdgcn_fdot2(__builtin_bit_cast(h2, w.y), __builtin_bit_cast(h2, v.y), acc, false);
    acc = __builtin_amdgcn_fdot2(__builtin_bit_cast(h2, w.z), __builtin_bit_cast(h2, v.z), acc, false);
    acc = __builtin_amdgcn_fdot2(__builtin_bit_cast(h2, w.w), __builtin_bit_cast(h2, v.w), acc, false);
#else
    const h2 w0 = __builtin_bit_cast(h2, w.x), v0 = __builtin_bit_cast(h2, v.x);
    const h2 w1 = __builtin_bit_cast(h2, w.y), v1 = __builtin_bit_cast(h2, v.y);
    const h2 w2 = __builtin_bit_cast(h2, w.z), v2 = __builtin_bit_cast(h2, v.z);
    const h2 w3 = __builtin_bit_cast(h2, w.w), v3 = __builtin_bit_cast(h2, v.w);
    acc += (float)w0.x*(float)v0.x + (float)w0.y*(float)v0.y
         + (float)w1.x*(float)v1.x + (float)w1.y*(float)v1.y
         + (float)w2.x*(float)v2.x + (float)w2.y*(float)v2.y
         + (float)w3.x*(float)v3.x + (float)w3.y*(float)v3.y;
#endif
    return acc;
}

__device__ __forceinline__ int xbase_of(int pos) {
    const int b = pos/(HO*WO), rem = pos%(HO*WO), ho = rem/WO, wo = rem%WO;
    return ((b*H_IN + ho)*W_IN + wo)*FIN*DI;
}

__device__ __forceinline__ int coff_of(int c) {
    const int slab = c >> 5, fin = c & 31;
    const int kh = slab/3, kw = slab%3;
    return (kh*W_IN + kw)*FIN*DI + fin*DI;
}

// ---- conversion (coalesced READS everywhere; scattered writes absorbed by L2)
__global__ __launch_bounds__(256) void kernConv(const float* __restrict__ Wt,
                                                const float* __restrict__ x,
                                                unsigned short* __restrict__ W2h,
                                                unsigned short* __restrict__ Wh,
                                                unsigned short* __restrict__ Ph) {
    const int b = blockIdx.x;
    if (b < CVT_W2H) {                 // W2h[c][o][f][i] <- W[f][c][o][i]
        const int idx = b*256 + threadIdx.x;       // linear over Wt rows (f*C+c)*DO+o
        const float* src = Wt + (size_t)idx*8;     // coalesced read
        const float4 a = *(const float4*)src;
        const float4 bb = *(const float4*)(src + 4);
        uint4 r;
        r.x = pack2(a.x, a.y);   r.y = pack2(a.z, a.w);
        r.z = pack2(bb.x, bb.y); r.w = pack2(bb.z, bb.w);
        const int o = idx & 15;
        const int c = (idx >> 4) % C;
        const int f = idx / (C*DO);
        ((uint4*)W2h)[(size_t)(c*DO + o)*F + f] = r;   // scattered write
    } else if (b < CVT_W2H + CVT_WH) { // Wh = fp16(Wt), same layout (copy-convert)
        const int idx = (b - CVT_W2H)*256 + threadIdx.x;   // 147456
        const float* src = Wt + (size_t)idx*8;
        const float4 a = *(const float4*)src;
        const float4 bb = *(const float4*)(src + 4);
        uint4 r;
        r.x = pack2(a.x, a.y);   r.y = pack2(a.z, a.w);
        r.z = pack2(bb.x, bb.y); r.w = pack2(bb.z, bb.w);
        ((uint4*)Wh)[idx] = r;
    } else {                           // Ph[pos][c*8+i]
        const int pc = (b - CVT_W2H - CVT_WH)*256 + threadIdx.x;  // 165888
        const int pos = pc / C, c = pc % C;
        const float* src = x + xbase_of(pos) + coff_of(c);
        const float4 a = *(const float4*)src;
        const float4 bb = *(const float4*)(src + 4);
        uint4 r;
        r.x = pack2(a.x, a.y);   r.y = pack2(a.z, a.w);
        r.z = pack2(bb.x, bb.y); r.w = pack2(bb.z, bb.w);
        ((uint4*)Ph)[pc] = r;
    }
}

// ---- kernM1: cent1 GEMM via MFMA + fused squash -> out1. ----------------------
// Block = (pos-tile pt, f-group fg); A-tile staged in LDS coalesced, shared by
// all 4 waves (f = wv*8 + fg). Per wave: C[m=pos][n=o] = P[16,2304] x W[f][.,16].
// A-frag: lane(m=lane&15, q=lane>>4) holds P[pos0+m][s*32 + q*8 + j], j=0..7.
// B-frag: lane(n=lane&15, q) holds W[f][c=s*4+q][o=n][i=j] (contiguous uint4).
// D: lane holds D[m=q*4+r][n=lane&15], r=0..3.
__global__ __launch_bounds__(256) void kernM1(const unsigned short* __restrict__ Ph,
                                              const unsigned short* __restrict__ Wh,
                                              float* __restrict__ out1)
{
    __shared__ unsigned short As[16][KPAD];       // 73,984 B

    const int tid  = threadIdx.x;
    const int lane = tid & 63;
    const int wv   = tid >> 6;
    const int pt   = blockIdx.x >> 3;             // 0..35
    const int fg   = blockIdx.x & 7;              // 0..7
    const int f    = wv*8 + fg;                   // all 32 f covered
    const int pos0 = pt*16;
    const int n    = lane & 15, q = lane >> 4;

    // stage A-tile: 4608 uint4, coalesced (row = linear/288, col8 = linear%288)
    #pragma unroll
    for (int r = 0; r < 18; ++r) {
        const int linear = r*256 + tid;
        const int row = linear / 288, col8 = linear % 288;
        const uint4 v = *(const uint4*)(Ph + (size_t)(pos0 + row)*KTOT + col8*8);
        *(uint4*)&As[row][col8*8] = v;
    }
    __syncthreads();

    const unsigned short* pa = &As[n][q*8];                          // A: m = lane&15
    const unsigned short* pb = Wh + ((size_t)(f*C + q)*DO + n)*DI;   // B: n = lane&15

    f4v acc0 = {0.f,0.f,0.f,0.f}, acc1 = {0.f,0.f,0.f,0.f};
    #pragma unroll 4
    for (int s = 0; s < KTOT/32; s += 2) {        // 72 steps, 2 chains
        const h8v a0 = *(const h8v*)(pa + s*32);
        const h8v b0 = *(const h8v*)(pb + (size_t)s*4*DO*DI);
        const h8v a1 = *(const h8v*)(pa + (s+1)*32);
        const h8v b1 = *(const h8v*)(pb + (size_t)(s+1)*4*DO*DI);
        acc0 = __builtin_amdgcn_mfma_f32_16x16x32_f16(a0, b0, acc0, 0, 0, 0);
        acc1 = __builtin_amdgcn_mfma_f32_16x16x32_f16(a1, b1, acc1, 0, 0, 0);
    }

    // epilogue: cent1 = D/32; squash over o (= lanes within each 16-group)
    #pragma unroll
    for (int r = 0; r < 4; ++r) {
        const float v = (acc0[r] + acc1[r]) * (1.f/32.f);
        float sq = v*v;
        sq += __shfl_xor(sq, 1);
        sq += __shfl_xor(sq, 2);
        sq += __shfl_xor(sq, 4);
        sq += __shfl_xor(sq, 8);
        const float sc = (sq/(1.f + sq)) * rsqrtf(sq + EPS);
        out1[(size_t)(pos0 + q*4 + r)*512 + f*DO + n] = v * sc;
    }
}

// ---- kern2: R15/R19-proven body; x from Ph (block-uniform scalar loads). ------
// writes part2[ch][pos][o][f] fp32
__global__ __launch_bounds__(256) void kern2n(const unsigned short* __restrict__ Ph,
                                              const unsigned short* __restrict__ W2h,
                                              const float* __restrict__ out1,
                                              float* __restrict__ part2)
{
    __shared__ float red[2][4][GP][32];  // 8 KB (dbuf)
    __shared__ float ccs[2][GP][32];     // 2 KB (dbuf)

    const int tid = threadIdx.x;
    const int f  = tid & 31;
    const int og = tid >> 5;            // 0..7
    const int o0 = 2*og, o1 = o0 + 1;
    const int wv = tid >> 6;            // wave 0..3
    const int half = (tid >> 5) & 1;    // og parity within wave
    const int ch = blockIdx.x & (CH-1);
    const int pg = blockIdx.x >> 4;     // 0..71

    int poff[GP];                       // block-uniform -> SGPRs
    #pragma unroll
    for (int p = 0; p < GP; ++p) poff[p] = (pg*GP + p)*KTOT;

    float u0[GP], u1[GP];
    #pragma unroll
    for (int p = 0; p < GP; ++p) {
        const float* up = out1 + (size_t)(pg*GP + p)*512 + f*DO;
        u0[p] = up[o0];
        u1[p] = up[o1];
    }

    const uint4* W2h4 = (const uint4*)W2h;
    const int c0 = ch*CC;

    float acc0[GP], acc1[GP];
    #pragma unroll
    for (int p = 0; p < GP; ++p) { acc0[p] = 0.f; acc1[p] = 0.f; }

    #pragma unroll 1
    for (int cl = 0; cl < CC; ++cl) {
        const int c = c0 + cl;
        const int buf = cl & 1;
        const uint4 w0 = W2h4[(size_t)(c*DO + o0)*F + f];
        const uint4 w1 = W2h4[(size_t)(c*DO + o1)*F + f];

        float pred0[GP], pred1[GP];
        #pragma unroll
        for (int p = 0; p < GP; ++p) {
            const uint4 xv = *(const uint4*)(Ph + poff[p] + c*DI);  // uniform
            pred0[p] = dot8h(w0, xv, 0.f);
            pred1[p] = dot8h(w1, xv, 0.f);
        }

        // agr partial over this thread's two o's; combine og-pairs via xor-32
        #pragma unroll
        for (int p = 0; p < GP; ++p) {
            float ap = pred0[p]*u0[p] + pred1[p]*u1[p];
            ap += __shfl_xor(ap, 32);
            if (half == 0) red[buf][wv][p][f] = ap;
        }
        __syncthreads();

        // remapped role: (p2, f2); finish f-sum, softmax over f, publish cc
        {
            const int p2 = tid >> 5, f2 = tid & 31;
            const float agr = red[buf][0][p2][f2] + red[buf][1][p2][f2]
                            + red[buf][2][p2][f2] + red[buf][3][p2][f2];
            float m = agr;
            m = fmaxf(m, __shfl_xor(m, 1));
            m = fmaxf(m, __shfl_xor(m, 2));
            m = fmaxf(m, __shfl_xor(m, 4));
            m = fmaxf(m, __shfl_xor(m, 8));
            m = fmaxf(m, __shfl_xor(m, 16));
            const float e = __expf(agr - m);
            float s = e;
            s += __shfl_xor(s, 1);
            s += __shfl_xor(s, 2);
            s += __shfl_xor(s, 4);
            s += __shfl_xor(s, 8);
            s += __shfl_xor(s, 16);
            ccs[buf][p2][f2] = e / s;
        }
        __syncthreads();

        // back to (f, og): accumulate cent2
        #pragma unroll
        for (int p = 0; p < GP; ++p) {
            const float cv = ccs[buf][p][f];
            acc0[p] += cv*pred0[p];
            acc1[p] += cv*pred1[p];
        }
    }

    #pragma unroll
    for (int p = 0; p < GP; ++p) {
        const size_t base = ((size_t)(ch*NPOS + pg*GP + p))*DO;
        part2[(base + o0)*F + f] = acc0[p];
        part2[(base + o1)*F + f] = acc1[p];
    }
}

// ---- kern3: reduce cent2 partials ([ch][pos][o][f]), squash, store. -----------
__global__ __launch_bounds__(256) void kern3(const float* __restrict__ part2,
                                             float* __restrict__ out)
{
    const int tid = threadIdx.x;
    const int f = tid & 31, p = tid >> 5;
    const int pos = blockIdx.x*8 + p;

    float cent[DO];
    #pragma unroll
    for (int o = 0; o < DO; ++o) cent[o] = 0.f;
    #pragma unroll 1
    for (int k = 0; k < CH; ++k) {
        const float* s = part2 + (size_t)(k*NPOS + pos)*512 + f;
        #pragma unroll
        for (int o = 0; o < DO; ++o) cent[o] += s[o*F];
    }
    float sn = 0.f;
    #pragma unroll
    for (int o = 0; o < DO; ++o) sn += cent[o]*cent[o];
    const float sc = (sn/(1.f + sn)) * rsqrtf(sn + EPS);
    float* dst = out + ((size_t)pos*F + f)*DO;
    #pragma unroll
    for (int o = 0; o < DO; ++o) dst[o] = cent[o]*sc;
}

// -------- fp32 single-kernel fallback (only if ws too small) -------------------
__device__ __forceinline__ float dot8(const float4* __restrict__ w,
                                      const float4 p0, const float4 p1) {
    float4 a = w[0], b = w[1];
    return a.x*p0.x + a.y*p0.y + a.z*p0.z + a.w*p0.w
         + b.x*p1.x + b.y*p1.y + b.z*p1.z + b.w*p1.w;
}

__global__ __launch_bounds__(256) void capsule_kernel_f32(
    const float* __restrict__ x, const float* __restrict__ Wt,
    float* __restrict__ out)
{
    __shared__ float patch[C*DI];
    __shared__ float cent[F*DO];
    __shared__ float out1[F*DO];
    __shared__ float agr[F*C];
    __shared__ float scale_s[F];

    const int tid = threadIdx.x;
    const int pos = blockIdx.x;
    const int b   = pos / (HO*WO);
    const int rem = pos % (HO*WO);
    const int ho  = rem / WO;
    const int wo  = rem % WO;

    #pragma unroll
    for (int slab = 0; slab < 9; ++slab) {
        const int kh = slab / 3, kw = slab % 3;
        const float* src = x + (((b*H_IN + ho + kh)*W_IN + (wo + kw))*FIN)*DI;
        patch[slab*256 + tid] = src[tid];
    }
    __syncthreads();

    const float4* pv = (const float4*)patch;

    {
        const int fo0 = tid, fo1 = tid + 256;
        const int f0 = fo0 >> 4, o0 = fo0 & 15;
        const int f1 = fo1 >> 4, o1 = fo1 & 15;
        float acc0 = 0.f, acc1 = 0.f;
        for (int c = 0; c < C; ++c) {
            const float4 p0 = pv[c*2], p1 = pv[c*2+1];
            acc0 += dot8((const float4*)(Wt + ((f0*C + c)*DO + o0)*DI), p0, p1);
            acc1 += dot8((const float4*)(Wt + ((f1*C + c)*DO + o1)*DI), p0, p1);
        }
        cent[fo0] = acc0 * (1.f/32.f);
        cent[fo1] = acc1 * (1.f/32.f);
    }
    __syncthreads();

    if (tid < F) {
        float sn = 0.f;
        #pragma unroll
        for (int o = 0; o < DO; ++o) { float v = cent[tid*DO + o]; sn += v*v; }
        const float sc = (sn/(1.f + sn)) * rsqrtf(sn + EPS);
        #pragma unroll
        for (int o = 0; o < DO; ++o) out1[tid*DO + o] = cent[tid*DO + o] * sc;
    }
    __syncthreads();

    #pragma unroll 1
    for (int r = 0; r < (F*C)/256; ++r) {
        const int pp = tid + 256*r;
        const int f = pp / C, c = pp % C;
        const float4* wrow = (const float4*)(Wt + (f*C + c)*DO*DI);
        const float4 p0 = pv[c*2], p1 = pv[c*2+1];
        float a = 0.f;
        #pragma unroll
        for (int o = 0; o < DO; ++o) a += dot8(wrow + o*2, p0, p1) * out1[f*DO + o];
        agr[pp] = a;
    }
    __syncthreads();

    for (int c = tid; c < C; c += 256) {
        float m = -1e30f;
        #pragma unroll
        for (int f = 0; f < F; ++f) m = fmaxf(m, agr[f*C + c]);
        float s = 0.f;
        #pragma unroll
        for (int f = 0; f < F; ++f) {
            const float e = __expf(agr[f*C + c] - m);
            agr[f*C + c] = e; s += e;
        }
        const float inv = 1.f / s;
        #pragma unroll
        for (int f = 0; f < F; ++f) agr[f*C + c] *= inv;
    }
    __syncthreads();

    {
        const int fo0 = tid, fo1 = tid + 256;
        const int f0 = fo0 >> 4, o0 = fo0 & 15;
        const int f1 = fo1 >> 4, o1 = fo1 & 15;
        float acc0 = 0.f, acc1 = 0.f;
        for (int c = 0; c < C; ++c) {
            const float4 p0 = pv[c*2], p1 = pv[c*2+1];
            acc0 += agr[f0*C + c] * dot8((const float4*)(Wt + ((f0*C + c)*DO + o0)*DI), p0, p1);
            acc1 += agr[f1*C + c] * dot8((const float4*)(Wt + ((f1*C + c)*DO + o1)*DI), p0, p1);
        }
        cent[fo0] = acc0;
        cent[fo1] = acc1;
    }
    __syncthreads();

    if (tid < F) {
        float sn = 0.f;
        #pragma unroll
        for (int o = 0; o < DO; ++o) { float v = cent[tid*DO + o]; sn += v*v; }
        scale_s[tid] = (sn/(1.f + sn)) * rsqrtf(sn + EPS);
    }
    __syncthreads();

    out[pos*(F*DO) + tid]       = cent[tid]       * scale_s[tid >> 4];
    out[pos*(F*DO) + tid + 256] = cent[tid + 256] * scale_s[(tid >> 4) + 16];
}

extern "C" void kernel_launch(void* const* d_in, const int* in_sizes, int n_in,
                              void* d_out, int out_size, void* d_ws, size_t ws_size,
                              hipStream_t stream) {
    const float* x  = (const float*)d_in[0];
    const float* Wt = (const float*)d_in[1];
    float* out = (float*)d_out;

    if (ws_size >= W2H_BYTES + WH_BYTES + PH_BYTES + PART_BYTES + OUT1_BYTES) {
        char* p = (char*)d_ws;
        unsigned short* W2h = (unsigned short*)p;            p += W2H_BYTES;
        unsigned short* Wh  = (unsigned short*)p;            p += WH_BYTES;
        unsigned short* Ph  = (unsigned short*)p;            p += PH_BYTES;
        float* part = (float*)p;                             p += PART_BYTES;
        float* out1 = (float*)p;

        kernConv<<<CVT_GRID, 256, 0, stream>>>(Wt, x, W2h, Wh, Ph);  // 1800 blocks
        kernM1<<<36*8, 256, 0, stream>>>(Ph, Wh, out1);              // 288 blocks
        kern2n<<<GRID, 256, 0, stream>>>(Ph, W2h, out1, part);       // 1152 blocks
        kern3<<<NPOS/8, 256, 0, stream>>>(part, out);                // 72 blocks
    } else {
        capsule_kernel_f32<<<NPOS, 256, 0, stream>>>(x, Wt, out);
    }
}